// Round 11
// baseline (649.794 us; speedup 1.0000x reference)
//
#include <hip/hip_runtime.h>
#include <hip/hip_cooperative_groups.h>
#include <hip/hip_bf16.h>

namespace cg = cooperative_groups;

// GCN 2-layer forward as ONE cooperative kernel (6 phases, grid.sync between):
//   P1 prep      : zero bucket cursors + W1,W2 -> bf16 transposed Wt[n][k]
//   P2 bin_edges : edges -> bucket-strided (src,dst) pairs (LDS-batched)
//   P3 build_csr : per-bucket histogram/prefix -> dinv,rbeg/rend,csr + u=bf16(z*dinv)
//   P4 agg PRE   : agg1 = bf16(u_d + sum u_s)     [half-wave: 2 nodes/wave]
//   P5 gemm12    : x1 = relu(dinv*(agg1@W1)+b1) in LDS; hs2 = bf16(dinv*(x1@W2))
//   P6 agg POST  : out = dinv*(hs2_d + sum hs2_s) + b2
// R10 lesson: gather needs small per-wave granularity (drain per node) ->
// aggregates stay node-parallel; gemm stays tile-parallel; phases separated
// by grid.sync instead of kernel boundaries (~18 us each in R9).

#define BSHIFT 8
#define NPB 256
#define CAP 5120
#define CH 4096
#define NBMAX 512
#define TILE 32
#define A_ST 72
#define X1_ST 136

typedef __attribute__((ext_vector_type(8))) short bf16x8;
typedef __attribute__((ext_vector_type(4))) float f32x4;

__device__ inline float bflo(unsigned int v) { return __uint_as_float(v << 16); }
__device__ inline float bfhi(unsigned int v) { return __uint_as_float(v & 0xFFFF0000u); }
__device__ inline unsigned short f32_to_bf16(float f) {
    unsigned int x = __float_as_uint(f);
    return (unsigned short)((x + 0x7FFFu + ((x >> 16) & 1u)) >> 16);   // RNE
}

struct GcnParams {
    const float* z; const int* src; const int* dst;
    const float* W1; const float* b1; const float* W2; const float* b2;
    float* out;
    float* dinv; int* rbeg; int* rend; int* bcursor;
    unsigned short* W1t; unsigned short* W2t;
    int* csr; int2* ebuf;
    unsigned short* u; unsigned short* agg1; unsigned short* hs2;
    int N, E, NB;
};

union Smem {
    struct { int hist[NBMAX]; int cur[NBMAX]; } bin;                       // 4 KB
    struct { int h[NPB]; int tmp[NPB]; float sdv[NPB]; } bc;               // 3 KB
    struct { unsigned short sA[TILE*A_ST]; unsigned short sX[TILE*X1_ST];
             float sdv[TILE]; } gm;                                        // 13.4 KB
};

__global__ __launch_bounds__(256, 4) void gcn_mega(GcnParams p) {
    cg::grid_group grd = cg::this_grid();
    __shared__ Smem sm;
    const int tid = threadIdx.x;
    const int gsz = gridDim.x;

    // ================= P1: prep =================
    for (int i = blockIdx.x * 256 + tid; i < 8192; i += gsz * 256) {
        if (i < p.NB) p.bcursor[i] = 0;
        { int n = i >> 6, k = i & 63;  p.W1t[i] = f32_to_bf16(p.W1[k * 128 + n]); }
        { int n = i >> 7, k = i & 127; p.W2t[i] = f32_to_bf16(p.W2[k * 64 + n]); }
    }
    grd.sync();

    // ================= P2: bin_edges =================
    const int nchunks = (p.E + CH - 1) / CH;
    for (int c = blockIdx.x; c < nchunks; c += gsz) {
        __syncthreads();                                   // LDS reuse guard
        for (int b = tid; b < p.NB; b += 256) sm.bin.hist[b] = 0;
        __syncthreads();
        const int e0 = c * CH;
#pragma unroll
        for (int j = 0; j < CH / 256; ++j) {
            int e = e0 + j * 256 + tid;
            if (e < p.E) atomicAdd(&sm.bin.hist[p.dst[e] >> BSHIFT], 1);
        }
        __syncthreads();
        for (int b = tid; b < p.NB; b += 256) {
            int cc = sm.bin.hist[b];
            sm.bin.cur[b] = (cc > 0) ? atomicAdd(&p.bcursor[b], cc) : 0;
        }
        __syncthreads();
#pragma unroll
        for (int j = 0; j < CH / 256; ++j) {
            int e = e0 + j * 256 + tid;
            if (e < p.E) {
                int s = p.src[e], d = p.dst[e];
                int b = d >> BSHIFT;
                int pos = atomicAdd(&sm.bin.cur[b], 1);
                p.ebuf[(size_t)b * CAP + pos] = make_int2(s, d);
            }
        }
    }
    grd.sync();

    // ================= P3: build_csr + u = bf16(z*dinv) =================
    for (int b = blockIdx.x; b < p.NB; b += gsz) {
        __syncthreads();
        const int n0  = b << BSHIFT;
        const int cnt = p.bcursor[b];
        const size_t base = (size_t)b * CAP;
        sm.bc.h[tid] = 0;
        __syncthreads();
        for (int i = tid; i < cnt; i += 256)
            atomicAdd(&sm.bc.h[p.ebuf[base + i].y - n0], 1);
        __syncthreads();
        int deg = sm.bc.h[tid];
        sm.bc.tmp[tid] = deg;
        __syncthreads();
        for (int off = 1; off < 256; off <<= 1) {
            int x = (tid >= off) ? sm.bc.tmp[tid - off] : 0;
            __syncthreads();
            sm.bc.tmp[tid] += x;
            __syncthreads();
        }
        int st = sm.bc.tmp[tid] - deg;
        int node = n0 + tid;
        float di = rsqrtf((float)deg + 1.0f);
        sm.bc.sdv[tid] = di;
        if (node < p.N) {
            p.dinv[node] = di;
            p.rbeg[node] = (int)base + st;
            p.rend[node] = (int)base + st + deg;
        }
        sm.bc.h[tid] = st;
        __syncthreads();
        for (int i = tid; i < cnt; i += 256) {
            int2 e = p.ebuf[base + i];
            int pos = atomicAdd(&sm.bc.h[e.y - n0], 1);
            p.csr[base + pos] = e.x;
        }
        const int nloc = (p.N - n0 < NPB) ? (p.N - n0) : NPB;
        for (int i = tid; i < nloc * 16; i += 256) {
            int r = i >> 4, kq = i & 15;
            float d2 = sm.bc.sdv[r];
            float4 v = ((const float4*)(p.z + (size_t)(n0 + r) * 64))[kq];
            ushort4 o;
            o.x = f32_to_bf16(v.x * d2); o.y = f32_to_bf16(v.y * d2);
            o.z = f32_to_bf16(v.z * d2); o.w = f32_to_bf16(v.w * d2);
            ((ushort4*)(p.u + (size_t)(n0 + r) * 64))[kq] = o;
        }
    }
    grd.sync();

    // ================= P4: aggregate PRE (half-wave per node) =================
    {
        const int wid  = (blockIdx.x * 256 + tid) >> 6;
        const int nw   = (gsz * 256) >> 6;
        const int half = (tid >> 5) & 1;
        const int f0   = (tid & 31) * 2;
        const int npairs = (p.N + 1) >> 1;
        for (int pp = wid; pp < npairs; pp += nw) {
            const int node = pp * 2 + half;
            float ax = 0.f, ay = 0.f;
            int e = 0, end = 0;
            if (node < p.N) {
                unsigned int sv = *(const unsigned int*)(p.u + (size_t)node * 64 + f0);
                ax = bflo(sv); ay = bfhi(sv);
                e = p.rbeg[node]; end = p.rend[node];
            }
            for (; e + 16 <= end; e += 16) {
                int s[16];
#pragma unroll
                for (int j = 0; j < 16; ++j) s[j] = p.csr[e + j];
                unsigned int v[16];
#pragma unroll
                for (int j = 0; j < 16; ++j)
                    v[j] = *(const unsigned int*)(p.u + (size_t)s[j] * 64 + f0);
#pragma unroll
                for (int j = 0; j < 16; ++j) { ax += bflo(v[j]); ay += bfhi(v[j]); }
            }
            for (; e + 4 <= end; e += 4) {
                int s0 = p.csr[e+0], s1 = p.csr[e+1], s2 = p.csr[e+2], s3 = p.csr[e+3];
                unsigned int v0 = *(const unsigned int*)(p.u + (size_t)s0 * 64 + f0);
                unsigned int v1 = *(const unsigned int*)(p.u + (size_t)s1 * 64 + f0);
                unsigned int v2 = *(const unsigned int*)(p.u + (size_t)s2 * 64 + f0);
                unsigned int v3 = *(const unsigned int*)(p.u + (size_t)s3 * 64 + f0);
                ax += (bflo(v0) + bflo(v1)) + (bflo(v2) + bflo(v3));
                ay += (bfhi(v0) + bfhi(v1)) + (bfhi(v2) + bfhi(v3));
            }
            for (; e < end; ++e) {
                unsigned int v = *(const unsigned int*)(p.u + (size_t)p.csr[e] * 64 + f0);
                ax += bflo(v); ay += bfhi(v);
            }
            if (node < p.N) {
                unsigned int o = (unsigned int)f32_to_bf16(ax)
                               | ((unsigned int)f32_to_bf16(ay) << 16);
                *(unsigned int*)(p.agg1 + (size_t)node * 64 + f0) = o;
            }
        }
    }
    grd.sync();

    // ================= P5: dual MFMA GEMM (tile grid-stride) =================
    {
        const int lane = tid & 63, wv = tid >> 6;
        const int l16 = lane & 15, quad = lane >> 4;
        const int ntiles = (p.N + TILE - 1) / TILE;
        for (int t0 = blockIdx.x; t0 < ntiles; t0 += gsz) {
            __syncthreads();                               // LDS reuse guard
            const int row0 = t0 * TILE;
            for (int i = tid; i < TILE * 8; i += 256) {
                int r = i >> 3, c = i & 7;
                int gr = row0 + r;
                uint4 v = make_uint4(0u, 0u, 0u, 0u);
                if (gr < p.N) v = *(const uint4*)(p.agg1 + (size_t)gr * 64 + c * 8);
                *(uint4*)&sm.gm.sA[r * A_ST + c * 8] = v;
            }
            if (tid < TILE) {
                int gr = row0 + tid;
                sm.gm.sdv[tid] = (gr < p.N) ? p.dinv[gr] : 0.0f;
            }
            __syncthreads();

            // phase 1: x1 = relu(dinv*(agg1@W1)+b1) -> sX
            {
                const int mt = wv & 1, ntb = (wv >> 1) * 4;
                f32x4 acc[4];
#pragma unroll
                for (int t = 0; t < 4; ++t) acc[t] = (f32x4)0.0f;
#pragma unroll
                for (int k0 = 0; k0 < 64; k0 += 32) {
                    bf16x8 af = *(const bf16x8*)&sm.gm.sA[(mt*16 + l16) * A_ST + k0 + quad*8];
#pragma unroll
                    for (int t = 0; t < 4; ++t) {
                        int ng = (ntb + t) * 16 + l16;
                        bf16x8 bf = *(const bf16x8*)&p.W1t[ng * 64 + k0 + quad*8];
                        acc[t] = __builtin_amdgcn_mfma_f32_16x16x32_bf16(af, bf, acc[t], 0, 0, 0);
                    }
                }
#pragma unroll
                for (int t = 0; t < 4; ++t) {
                    int col = (ntb + t) * 16 + l16;
                    float bb = p.b1[col];
#pragma unroll
                    for (int r = 0; r < 4; ++r) {
                        int lr = mt * 16 + quad * 4 + r;
                        float o = fmaxf(acc[t][r] * sm.gm.sdv[lr] + bb, 0.0f);
                        sm.gm.sX[lr * X1_ST + col] = f32_to_bf16(o);
                    }
                }
            }
            __syncthreads();

            // phase 2: hs2 = bf16(dinv*(x1@W2))
            {
                const int mt = wv & 1, ntb = (wv >> 1) * 2;
                f32x4 acc[2];
#pragma unroll
                for (int t = 0; t < 2; ++t) acc[t] = (f32x4)0.0f;
#pragma unroll
                for (int k0 = 0; k0 < 128; k0 += 32) {
                    bf16x8 af = *(const bf16x8*)&sm.gm.sX[(mt*16 + l16) * X1_ST + k0 + quad*8];
#pragma unroll
                    for (int t = 0; t < 2; ++t) {
                        int ng = (ntb + t) * 16 + l16;
                        bf16x8 bf = *(const bf16x8*)&p.W2t[ng * 128 + k0 + quad*8];
                        acc[t] = __builtin_amdgcn_mfma_f32_16x16x32_bf16(af, bf, acc[t], 0, 0, 0);
                    }
                }
#pragma unroll
                for (int t = 0; t < 2; ++t) {
                    int col = (ntb + t) * 16 + l16;
#pragma unroll
                    for (int r = 0; r < 4; ++r) {
                        int lr = mt * 16 + quad * 4 + r;
                        int gr = row0 + lr;
                        if (gr < p.N)
                            p.hs2[(size_t)gr * 64 + col] = f32_to_bf16(acc[t][r] * sm.gm.sdv[lr]);
                    }
                }
            }
        }
    }
    grd.sync();

    // ================= P6: aggregate POST (half-wave per node) =================
    {
        const int wid  = (blockIdx.x * 256 + tid) >> 6;
        const int nw   = (gsz * 256) >> 6;
        const int half = (tid >> 5) & 1;
        const int f0   = (tid & 31) * 2;
        const int npairs = (p.N + 1) >> 1;
        for (int pp = wid; pp < npairs; pp += nw) {
            const int node = pp * 2 + half;
            float ax = 0.f, ay = 0.f;
            int e = 0, end = 0;
            if (node < p.N) {
                unsigned int sv = *(const unsigned int*)(p.hs2 + (size_t)node * 64 + f0);
                ax = bflo(sv); ay = bfhi(sv);
                e = p.rbeg[node]; end = p.rend[node];
            }
            for (; e + 16 <= end; e += 16) {
                int s[16];
#pragma unroll
                for (int j = 0; j < 16; ++j) s[j] = p.csr[e + j];
                unsigned int v[16];
#pragma unroll
                for (int j = 0; j < 16; ++j)
                    v[j] = *(const unsigned int*)(p.hs2 + (size_t)s[j] * 64 + f0);
#pragma unroll
                for (int j = 0; j < 16; ++j) { ax += bflo(v[j]); ay += bfhi(v[j]); }
            }
            for (; e + 4 <= end; e += 4) {
                int s0 = p.csr[e+0], s1 = p.csr[e+1], s2 = p.csr[e+2], s3 = p.csr[e+3];
                unsigned int v0 = *(const unsigned int*)(p.hs2 + (size_t)s0 * 64 + f0);
                unsigned int v1 = *(const unsigned int*)(p.hs2 + (size_t)s1 * 64 + f0);
                unsigned int v2 = *(const unsigned int*)(p.hs2 + (size_t)s2 * 64 + f0);
                unsigned int v3 = *(const unsigned int*)(p.hs2 + (size_t)s3 * 64 + f0);
                ax += (bflo(v0) + bflo(v1)) + (bflo(v2) + bflo(v3));
                ay += (bfhi(v0) + bfhi(v1)) + (bfhi(v2) + bfhi(v3));
            }
            for (; e < end; ++e) {
                unsigned int v = *(const unsigned int*)(p.hs2 + (size_t)p.csr[e] * 64 + f0);
                ax += bflo(v); ay += bfhi(v);
            }
            if (node < p.N) {
                float di = p.dinv[node];
                float2 o;
                o.x = di * ax + p.b2[f0];
                o.y = di * ay + p.b2[f0 + 1];
                *(float2*)(p.out + (size_t)node * 64 + f0) = o;
            }
        }
    }
}

static inline size_t align_up(size_t x, size_t a) { return (x + a - 1) / a * a; }

extern "C" void kernel_launch(void* const* d_in, const int* in_sizes, int n_in,
                              void* d_out, int out_size, void* d_ws, size_t ws_size,
                              hipStream_t stream) {
    const float* z    = (const float*)d_in[0];   // [N,64]
    const int*   eidx = (const int*)d_in[1];     // [2,E]: src row then dst row
    const float* W1   = (const float*)d_in[2];   // [64,128]
    const float* b1   = (const float*)d_in[3];   // [128]
    const float* W2   = (const float*)d_in[4];   // [128,64]
    const float* b2   = (const float*)d_in[5];   // [64]

    const int N = in_sizes[0] / 64;
    const int E = in_sizes[1] / 2;
    const int NB = (N + NPB - 1) >> BSHIFT;

    // Workspace: small | W1t | W2t | csr | bufA(u) | bufB(hs2) | bufC(ebuf->agg1)
    char* ws = (char*)d_ws;
    size_t off = 0;
    float* dinv    = (float*)(ws + off); off = align_up(off + (size_t)N * 4, 512);
    int*   rbeg    = (int*)  (ws + off); off = align_up(off + (size_t)N * 4, 512);
    int*   rend    = (int*)  (ws + off); off = align_up(off + (size_t)N * 4, 512);
    int*   bcursor = (int*)  (ws + off); off = align_up(off + (size_t)NBMAX * 4, 512);
    unsigned short* W1t = (unsigned short*)(ws + off); off = align_up(off + 8192 * 2, 512);
    unsigned short* W2t = (unsigned short*)(ws + off); off = align_up(off + 8192 * 2, 512);
    int*   csr     = (int*)  (ws + off); off = align_up(off + (size_t)NB * CAP * 4, 512);
    float* bufA    = (float*)(ws + off); off = align_up(off + (size_t)N * 64 * 4, 512);
    float* bufB    = (float*)(ws + off); off = align_up(off + (size_t)N * 64 * 4, 512);
    float* bufC    = (float*)(ws + off); off = align_up(off + (size_t)N * 128 * 4, 512);
    (void)ws_size;

    GcnParams prm;
    prm.z = z; prm.src = eidx; prm.dst = eidx + E;
    prm.W1 = W1; prm.b1 = b1; prm.W2 = W2; prm.b2 = b2;
    prm.out = (float*)d_out;
    prm.dinv = dinv; prm.rbeg = rbeg; prm.rend = rend; prm.bcursor = bcursor;
    prm.W1t = W1t; prm.W2t = W2t;
    prm.csr = csr; prm.ebuf = (int2*)bufC;            // ebuf dead after P3
    prm.u = (unsigned short*)bufA;
    prm.agg1 = (unsigned short*)bufC;                 // reuses ebuf space (after P3)
    prm.hs2 = (unsigned short*)bufB;
    prm.N = N; prm.E = E; prm.NB = NB;

    int dev = 0;
    hipGetDevice(&dev);
    int nCU = 256;
    hipDeviceGetAttribute(&nCU, hipDeviceAttributeMultiprocessorCount, dev);
    int maxB = 0;
    hipOccupancyMaxActiveBlocksPerMultiprocessor(&maxB, gcn_mega, 256, 0);
    int bpc = maxB < 1 ? 1 : (maxB > 8 ? 8 : maxB);

    void* args[] = { &prm };
    hipLaunchCooperativeKernel(gcn_mega, dim3(nCU * bpc), dim3(256), args, 0, stream);
}